// Round 1
// baseline (402.332 us; speedup 1.0000x reference)
//
#include <hip/hip_runtime.h>
#include <hip/hip_cooperative_groups.h>
#include <cstdint>

namespace cg = cooperative_groups;

#define B_ 4
#define S_ 4096
#define D_ 512
#define M_ (B_*S_)   // 16384 rows

typedef _Float16 f16;
typedef _Float16 f16x8 __attribute__((ext_vector_type(8)));
typedef _Float16 f16x2 __attribute__((ext_vector_type(2)));
typedef float    f32x4 __attribute__((ext_vector_type(4)));

typedef __attribute__((address_space(1))) void* as1p;
typedef __attribute__((address_space(3))) void* as3p;

__device__ __forceinline__ void gl2lds16(const void* g, void* l) {
    __builtin_amdgcn_global_load_lds((as1p)g, (as3p)l, 16, 0, 0);
}

union f16pack { f16x8 v8; f16x2 v2[4]; };

// ---------------- P0a: weight transpose/cast job (v = 0..255) ----------------
__device__ __forceinline__ void weight_job(int v, int t, char* SMEM,
    const float* __restrict__ Wv, const float* __restrict__ Wk,
    const float* __restrict__ Wq, const float* __restrict__ Wl,
    f16* __restrict__ WvT, f16* __restrict__ WkT, f16* __restrict__ WqT,
    f16* __restrict__ WlH)
{
    const int z = v >> 6, tile_id = v & 63;
    const int bx = tile_id & 7, by = tile_id >> 3;
    if (z == 3) {    // Wl cast (row-major f16), no LDS
        const size_t base = (size_t)tile_id*4096 + (size_t)t*16;
        const float4* s4 = (const float4*)(Wl + base);
        float4 a0 = s4[0], a1 = s4[1], a2 = s4[2], a3 = s4[3];
        f16x8 o0, o1;
        o0[0]=(f16)a0.x; o0[1]=(f16)a0.y; o0[2]=(f16)a0.z; o0[3]=(f16)a0.w;
        o0[4]=(f16)a1.x; o0[5]=(f16)a1.y; o0[6]=(f16)a1.z; o0[7]=(f16)a1.w;
        o1[0]=(f16)a2.x; o1[1]=(f16)a2.y; o1[2]=(f16)a2.z; o1[3]=(f16)a2.w;
        o1[4]=(f16)a3.x; o1[5]=(f16)a3.y; o1[6]=(f16)a3.z; o1[7]=(f16)a3.w;
        *(f16x8*)(WlH + base)     = o0;
        *(f16x8*)(WlH + base + 8) = o1;
        return;
    }
    // transpose tile (row stride 68 floats -> float4 stores at {0,64,128,192} aligned)
    float (*tile)[68] = (float(*)[68])SMEM;
    const float* src = (z == 0) ? Wv : ((z == 1) ? Wk : Wq);
    f16* dst = (z == 0) ? WvT : ((z == 1) ? WkT : WqT);
    const int i0 = bx*64, j0 = by*64;
    const int r = t >> 2, cpart = (t & 3)*16;
    {
        const float4* s4 = (const float4*)(src + (size_t)(i0 + r)*512 + j0 + cpart);
        float4 a0 = s4[0], a1 = s4[1], a2 = s4[2], a3 = s4[3];
        *(float4*)&tile[r][cpart]    = a0;
        *(float4*)&tile[r][cpart+4]  = a1;
        *(float4*)&tile[r][cpart+8]  = a2;
        *(float4*)&tile[r][cpart+12] = a3;
    }
    __syncthreads();
    const int c = t >> 2, rpart = (t & 3)*16;
    f16x8 o0, o1;
    #pragma unroll
    for (int q = 0; q < 8; q++) o0[q] = (f16)tile[rpart + q][c];
    #pragma unroll
    for (int q = 0; q < 8; q++) o1[q] = (f16)tile[rpart + 8 + q][c];
    *(f16x8*)(dst + (size_t)(j0 + c)*512 + i0 + rpart)     = o0;
    *(f16x8*)(dst + (size_t)(j0 + c)*512 + i0 + rpart + 8) = o1;
}

// ---------------- xs cast + column-sum job (j = 0..511, 32 rows each) ----------------
__device__ __forceinline__ void xs_job(int j, int t, char* SMEM,
    const float* __restrict__ xs, f16* __restrict__ xs_h,
    float* __restrict__ xsSum)
{
    float* red = (float*)SMEM;   // [4][512]
    const int w = t >> 6, l = t & 63;
    const int col = l * 8;
    float acc[8] = {0,0,0,0,0,0,0,0};
    for (int c = 0; c < 8; c++) {
        int row = j*32 + c*4 + w;
        const float4* p = (const float4*)(xs + (size_t)row*512 + col);
        float4 a = p[0], b = p[1];
        f16x8 o;
        o[0]=(f16)a.x; o[1]=(f16)a.y; o[2]=(f16)a.z; o[3]=(f16)a.w;
        o[4]=(f16)b.x; o[5]=(f16)b.y; o[6]=(f16)b.z; o[7]=(f16)b.w;
        *(f16x8*)(xs_h + (size_t)row*512 + col) = o;
        acc[0]+=a.x; acc[1]+=a.y; acc[2]+=a.z; acc[3]+=a.w;
        acc[4]+=b.x; acc[5]+=b.y; acc[6]+=b.z; acc[7]+=b.w;
    }
    #pragma unroll
    for (int q = 0; q < 8; q++) red[w*512 + col + q] = acc[q];
    __syncthreads();
    const int b = j >> 7;
    #pragma unroll
    for (int k = 0; k < 2; k++) {
        int c = t + k*256;
        atomicAdd(&xsSum[b*512 + c], red[c] + red[512+c] + red[1024+c] + red[1536+c]);
    }
}

// ---------------- wmm job (blk = 0..191): MFMA weight GEMMs ----------------
__device__ __forceinline__ void wmm_job(int blk, int t, char* SMEM,
    const f16* __restrict__ WlH, const f16* __restrict__ WvT,
    const f16* __restrict__ WkT, const f16* __restrict__ WqT,
    const float* __restrict__ Wl, const float* __restrict__ bv,
    const float* __restrict__ bk, const float* __restrict__ bq,
    f16* __restrict__ WvlH, float* __restrict__ bvlG,
    float* __restrict__ Mm, float* __restrict__ MT,
    float* __restrict__ t1, float* __restrict__ t2, float* __restrict__ t12)
{
    f16* lA = (f16*)SMEM;          // 64*32 f16 = 4KB
    f16* lB = lA + 64*32;          // 4KB
    const int z = blk >> 6, rr = blk & 63;
    const int bx = rr & 7, by = rr >> 3;
    const int i0 = bx*64, j0 = by*64;
    const int lane = t & 63, wid = t >> 6;
    const int wm = (wid & 1)*32, wn = (wid >> 1)*32;
    const f16* A = (z == 0) ? WlH : ((z == 1) ? WkT : WqT);
    const f16* B = (z == 0) ? WvT : ((z == 1) ? WqT : WkT);
    const int srow = t >> 2, skb = (t & 3) << 4;
    const long aoff = (long)(i0 + srow)*1024 + skb;
    const long boff = (long)(j0 + srow)*1024 + skb;
    const unsigned wbase = (unsigned)wid << 10;
    const bool doT1 = (z == 1) && (bx == 0);
    const bool doT2 = (z == 1) && (by == 0);
    const int jj = t >> 2, kq = (t & 3)*8;

    f32x4 acc[2][2] = {};
    float t1a = 0.f, t2a = 0.f;
    const int ael = (wm + (lane & 15))*32 + ((lane >> 4) << 3);
    const int bel = (wn + (lane & 15))*32 + ((lane >> 4) << 3);

    for (int k0 = 0; k0 < 512; k0 += 32) {
        __syncthreads();
        gl2lds16((const char*)A + aoff + k0*2, (char*)lA + wbase);
        gl2lds16((const char*)B + boff + k0*2, (char*)lB + wbase);
        __syncthreads();
        f16x8 af[2], bf[2];
        af[0] = *(const f16x8*)(lA + ael);
        af[1] = *(const f16x8*)(lA + ael + 512);
        bf[0] = *(const f16x8*)(lB + bel);
        bf[1] = *(const f16x8*)(lB + bel + 512);
        #pragma unroll
        for (int i = 0; i < 2; i++)
            #pragma unroll
            for (int j = 0; j < 2; j++)
                acc[i][j] = __builtin_amdgcn_mfma_f32_16x16x32_f16(af[i], bf[j], acc[i][j], 0, 0, 0);
        if (doT1) {
            float4 b0 = *(const float4*)(bk + k0 + kq);
            float4 b1 = *(const float4*)(bk + k0 + kq + 4);
            float bb[8] = {b0.x,b0.y,b0.z,b0.w,b1.x,b1.y,b1.z,b1.w};
            #pragma unroll
            for (int q = 0; q < 8; q++) t1a += (float)lB[jj*32 + kq + q] * bb[q];
        }
        if (doT2) {
            float4 b0 = *(const float4*)(bq + k0 + kq);
            float4 b1 = *(const float4*)(bq + k0 + kq + 4);
            float bb[8] = {b0.x,b0.y,b0.z,b0.w,b1.x,b1.y,b1.z,b1.w};
            #pragma unroll
            for (int q = 0; q < 8; q++) t2a += (float)lA[jj*32 + kq + q] * bb[q];
        }
    }

    const int rb = wm + ((lane >> 4) << 2);
    const int cb = wn + (lane & 15);
    if (z == 0) {
        #pragma unroll
        for (int i = 0; i < 2; i++)
            #pragma unroll
            for (int j = 0; j < 2; j++)
                #pragma unroll
                for (int r = 0; r < 4; r++)
                    WvlH[(size_t)(i0 + rb + i*16 + r)*512 + j0 + cb + j*16] = (f16)acc[i][j][r];
        if (by == 0) {
            int r = t >> 2, part = t & 3;
            const float4* wr = (const float4*)(Wl + (size_t)(i0+r)*512 + part*128);
            const float4* bp = (const float4*)(bv + part*128);
            float s = 0.f;
            #pragma unroll 8
            for (int q = 0; q < 32; q++) {
                float4 wv4 = wr[q], b4 = bp[q];
                s += wv4.x*b4.x + wv4.y*b4.y + wv4.z*b4.z + wv4.w*b4.w;
            }
            s += __shfl_xor(s, 1);
            s += __shfl_xor(s, 2);
            if (part == 0) bvlG[i0 + r] = s;
        }
    } else {
        float* Cout = (z == 1) ? Mm : MT;
        #pragma unroll
        for (int i = 0; i < 2; i++)
            #pragma unroll
            for (int j = 0; j < 2; j++)
                #pragma unroll
                for (int r = 0; r < 4; r++)
                    Cout[(size_t)(i0 + rb + i*16 + r)*512 + j0 + cb + j*16] = acc[i][j][r];
        if (doT1) {
            t1a += __shfl_xor(t1a, 1);
            t1a += __shfl_xor(t1a, 2);
            if ((lane & 3) == 0) t1[j0 + jj] = t1a;
        }
        if (doT2) {
            t2a += __shfl_xor(t2a, 1);
            t2a += __shfl_xor(t2a, 2);
            if ((lane & 3) == 0) t2[i0 + jj] = t2a;
        }
        if (z == 1 && rr == 0 && wid == 0) {
            float s = 0.f;
            #pragma unroll
            for (int q = 0; q < 8; q++) s += bk[lane + q*64]*bq[lane + q*64];
            #pragma unroll
            for (int m = 1; m < 64; m <<= 1) s += __shfl_xor(s, m);
            if (lane == 0) *t12 = s;
        }
    }
}

// ---------------- mva job (blk = 0..32) ----------------
__device__ __forceinline__ void mva_job(int blk, int t,
    const float* __restrict__ W, const float* __restrict__ vin,
    const float* __restrict__ bias2, const float* __restrict__ bias3,
    const float* __restrict__ betaG, const float* __restrict__ t12G,
    float* __restrict__ oput, f16* __restrict__ oput_h, float* __restrict__ cG)
{
    const int w = t >> 6, l = t & 63;
    if (blk == 32) {
        const float4* b4 = (const float4*)(bias3 + l*8);
        const float4* v4 = (const float4*)(vin + w*512 + l*8);
        float4 b0 = b4[0], b1 = b4[1], v0 = v4[0], v1 = v4[1];
        float s = b0.x*v0.x + b0.y*v0.y + b0.z*v0.z + b0.w*v0.w
                + b1.x*v1.x + b1.y*v1.y + b1.z*v1.z + b1.w*v1.w;
        #pragma unroll
        for (int m = 1; m < 64; m <<= 1) s += __shfl_xor(s, m);
        if (l == 0) {
            float beta = betaG ? betaG[w] : 4096.0f;
            cG[w] = s + beta * (*t12G);
        }
        return;
    }
    float vb[4][8];
    #pragma unroll
    for (int b = 0; b < 4; b++) {
        float4 p0 = *(const float4*)(vin + b*512 + l*8);
        float4 p1 = *(const float4*)(vin + b*512 + l*8 + 4);
        vb[b][0]=p0.x; vb[b][1]=p0.y; vb[b][2]=p0.z; vb[b][3]=p0.w;
        vb[b][4]=p1.x; vb[b][5]=p1.y; vb[b][6]=p1.z; vb[b][7]=p1.w;
    }
    const int r0 = blk*16 + w*4;
    float res[4][4];
    #pragma unroll
    for (int r = 0; r < 4; r++) {
        const float4* wr = (const float4*)(W + (size_t)(r0+r)*512 + l*8);
        float4 a = wr[0], c = wr[1];
        float wv[8] = {a.x,a.y,a.z,a.w,c.x,c.y,c.z,c.w};
        #pragma unroll
        for (int b = 0; b < 4; b++) {
            float s = 0.f;
            #pragma unroll
            for (int q = 0; q < 8; q++) s += wv[q]*vb[b][q];
            res[r][b] = s;
        }
    }
    #pragma unroll
    for (int r = 0; r < 4; r++)
        #pragma unroll
        for (int b = 0; b < 4; b++)
            #pragma unroll
            for (int m = 1; m < 64; m <<= 1) res[r][b] += __shfl_xor(res[r][b], m);
    if (l < 4) {
        const float beta = betaG ? betaG[l] : 4096.0f;
        #pragma unroll
        for (int r = 0; r < 4; r++) {
            float val = res[r][l] + beta*bias2[r0 + r];
            oput[l*512 + r0 + r] = val;
            if (oput_h) oput_h[l*512 + r0 + r] = (f16)val;
        }
    }
}

// ---------------- z job (blk = 0..511, 32 rows each) ----------------
__device__ __forceinline__ void z_job(int blk, int t, char* SMEM,
    const f16* __restrict__ xs_h, const float* __restrict__ hG,
    const float* __restrict__ c1G, float* __restrict__ yG, float* __restrict__ S0G)
{
    float* hs    = (float*)SMEM;      // 512
    float* yred  = hs + 512;          // [4][512]
    float* s0red = yred + 2048;       // [4]
    const int b = blk >> 7, w = t >> 6, l = t & 63;
    hs[t] = hG[b*512 + t]; hs[t+256] = hG[b*512 + t + 256];
    __syncthreads();
    const float c1 = c1G[b];
    float hx[8];
    #pragma unroll
    for (int q = 0; q < 8; q++) hx[q] = hs[l*8+q];
    float yacc[8] = {0,0,0,0,0,0,0,0};
    float s0acc = 0.f;
    for (int it = 0; it < 8; it++) {
        int row = blk*32 + w*8 + it;
        f16x8 v = *(const f16x8*)(xs_h + (size_t)row*512 + l*8);
        float xf[8];
        #pragma unroll
        for (int q = 0; q < 8; q++) xf[q] = (float)v[q];
        float d = 0.f;
        #pragma unroll
        for (int q = 0; q < 8; q++) d += xf[q]*hx[q];
        #pragma unroll
        for (int m = 1; m < 64; m <<= 1) d += __shfl_xor(d, m);
        float z  = 4096.0f + (d + c1)*(1.0f/512.0f);
        float iv = 1.0f/z;
        s0acc += iv;
        #pragma unroll
        for (int q = 0; q < 8; q++) yacc[q] += iv*xf[q];
    }
    #pragma unroll
    for (int q = 0; q < 8; q++) yred[w*512 + l*8+q] = yacc[q];
    if (l == 0) s0red[w] = s0acc;
    __syncthreads();
    #pragma unroll
    for (int k = 0; k < 2; k++) {
        int c = t + k*256;
        atomicAdd(&yG[b*512 + c], yred[c]+yred[512+c]+yred[1024+c]+yred[1536+c]);
    }
    if (t == 0) atomicAdd(&S0G[b], s0red[0]+s0red[1]+s0red[2]+s0red[3]);
}

// ---------------- cooperative front kernel: P0..P4 ----------------
__global__ __launch_bounds__(256, 2) void front_kernel(
    const float* __restrict__ xs,
    const float* __restrict__ Wv, const float* __restrict__ Wk,
    const float* __restrict__ Wq, const float* __restrict__ Wl,
    const float* __restrict__ bv, const float* __restrict__ bk,
    const float* __restrict__ bq,
    f16* __restrict__ xs_h, float* __restrict__ xsSum,
    f16* __restrict__ WvT, f16* __restrict__ WkT, f16* __restrict__ WqT,
    f16* __restrict__ WlH, f16* __restrict__ WvlH, float* __restrict__ bvlG,
    float* __restrict__ Mm, float* __restrict__ MT,
    float* __restrict__ t1, float* __restrict__ t2, float* __restrict__ t12,
    float* __restrict__ hG, float* __restrict__ c1G,
    float* __restrict__ yG, float* __restrict__ S0G,
    float* __restrict__ uG, f16* __restrict__ uH, float* __restrict__ c2G)
{
    __shared__ __attribute__((aligned(16))) char SMEM[17408];  // max over phases (64x68 f32 tile)
    cg::grid_group grid = cg::this_grid();
    const int blk = blockIdx.x;
    const int t = threadIdx.x;

    // P0: weight transposes (blocks 0..255) || xs rows 0..8191 (blocks 256..511)
    if (blk < 256) weight_job(blk, t, SMEM, Wv, Wk, Wq, Wl, WvT, WkT, WqT, WlH);
    else           xs_job(blk - 256, t, SMEM, xs, xs_h, xsSum);
    grid.sync();

    // P1: weight GEMMs (blocks 0..191) || xs rows 8192..16383 (blocks 192..447)
    if (blk < 192)      wmm_job(blk, t, SMEM, WlH, WvT, WkT, WqT, Wl, bv, bk, bq,
                                WvlH, bvlG, Mm, MT, t1, t2, t12);
    else if (blk < 448) xs_job(blk - 192 + 256, t, SMEM, xs, xs_h, xsSum);
    grid.sync();

    // P2: hG = MT@xsSum + 4096*t1 ; c1 = t2.xsSum + 4096*t12
    if (blk < 33) mva_job(blk, t, MT, xsSum, t1, t2, (const float*)nullptr, t12,
                          hG, (f16*)nullptr, c1G);
    grid.sync();

    // P3: z pass (all 512 blocks, 32 rows each)
    z_job(blk, t, SMEM, xs_h, hG, c1G, yG, S0G);
    grid.sync();

    // P4: uG = Mm@y + S0*t2 ; c2 = t1.y + S0*t12 ; uH f16 copy
    if (blk < 33) mva_job(blk, t, Mm, yG, t2, t1, S0G, t12, uG, uH, c2G);
}

// ---------------- vl_gemm: out = tanh(rs*(xs@Wvl^T + bvl) + bl), rs fused via v_dot2 ----------------
__global__ __launch_bounds__(256, 2) void vl_gemm(const f16* __restrict__ A,
    const f16* __restrict__ Bt, const float* __restrict__ bvlG,
    const float* __restrict__ blG, const f16* __restrict__ uH,
    const float* __restrict__ c2G, const float* __restrict__ S0G,
    float* __restrict__ out)
{
    constexpr int K = 512;
    __shared__ f16 lA[128*32];
    __shared__ f16 lB[128*32];
    __shared__ float rsbuf[128];
    const int t = threadIdx.x;
    const int m0 = blockIdx.x*128, n0 = blockIdx.y*128;
    const int lane = t & 63, wid = t >> 6;
    const int wm = (wid & 1) << 6, wn = (wid >> 1) << 6;
    const int srow = t >> 2, skb = (t & 3) << 4;
    const long aoff0 = (long)(m0 + srow)*(K*2) + skb;
    const long aoff1 = aoff0 + 64L*(K*2);
    const long boff0 = (long)(n0 + srow)*(K*2) + skb;
    const long boff1 = boff0 + 64L*(K*2);
    char* ldsA = (char*)lA;
    char* ldsB = (char*)lB;
    const unsigned wbase = (unsigned)wid << 10;
    const char* Ab = (const char*)A;
    const char* Bb = (const char*)Bt;

    const int bat = blockIdx.x >> 5;          // 32 m-tiles per batch
    const f16* u = uH + bat*512;
    const int ku = (lane >> 4) << 3;

    f32x4 acc[4][4] = {};
    float racc[4] = {0.f,0.f,0.f,0.f};
    const int ael = (wm + (lane & 15))*32 + ku;
    const int bel = (wn + (lane & 15))*32 + ku;

    for (int k0 = 0; k0 < K; k0 += 32) {
        __syncthreads();
        const long kb = (long)k0*2;
        gl2lds16(Ab + aoff0 + kb, ldsA + wbase);
        gl2lds16(Ab + aoff1 + kb, ldsA + 4096 + wbase);
        gl2lds16(Bb + boff0 + kb, ldsB + wbase);
        gl2lds16(Bb + boff1 + kb, ldsB + 4096 + wbase);
        __syncthreads();
        f16x8 af[4], bf[4];
        #pragma unroll
        for (int i = 0; i < 4; i++) af[i] = *(const f16x8*)(lA + ael + i*512);
        #pragma unroll
        for (int j = 0; j < 4; j++) bf[j] = *(const f16x8*)(lB + bel + j*512);
        f16pack up; up.v8 = *(const f16x8*)(u + k0 + ku);
        #pragma unroll
        for (int i = 0; i < 4; i++) {
            f16pack ap; ap.v8 = af[i];
            #pragma unroll
            for (int q = 0; q < 4; q++)
                racc[i] = __builtin_amdgcn_fdot2(ap.v2[q], up.v2[q], racc[i], false);
        }
        #pragma unroll
        for (int i = 0; i < 4; i++)
            #pragma unroll
            for (int j = 0; j < 4; j++)
                acc[i][j] = __builtin_amdgcn_mfma_f32_16x16x32_f16(af[i], bf[j], acc[i][j], 0, 0, 0);
    }

    #pragma unroll
    for (int i = 0; i < 4; i++) {
        racc[i] += __shfl_xor(racc[i], 16);
        racc[i] += __shfl_xor(racc[i], 32);
    }
    const float S0 = S0G[bat], c2 = c2G[bat];
    if (wid < 2 && lane < 16) {
        #pragma unroll
        for (int i = 0; i < 4; i++)
            rsbuf[wm + i*16 + lane] = S0 + (racc[i] + c2)*(1.0f/512.0f);
    }
    __syncthreads();

    const int crb = m0 + wm + ((lane >> 4) << 2);
    const int ccb = n0 + wn + (lane & 15);
    const int lrb = wm + ((lane >> 4) << 2);
    #pragma unroll
    for (int i = 0; i < 4; i++) {
        float rsv[4];
        #pragma unroll
        for (int r = 0; r < 4; r++) rsv[r] = rsbuf[lrb + i*16 + r];
        #pragma unroll
        for (int j = 0; j < 4; j++) {
            int c = ccb + j*16;
            float bb = bvlG[c], bo = blG[c];
            #pragma unroll
            for (int r = 0; r < 4; r++) {
                float yv = rsv[r]*(acc[i][j][r] + bb) + bo;
                float e2 = __expf(2.0f*yv);
                out[(size_t)(crb + i*16 + r)*512 + c] = 1.0f - 2.0f/(e2 + 1.0f);
            }
        }
    }
}

extern "C" void kernel_launch(void* const* d_in, const int* in_sizes, int n_in,
                              void* d_out, int out_size, void* d_ws, size_t ws_size,
                              hipStream_t stream)
{
    const float* xs = (const float*)d_in[0];
    const float* Wk = (const float*)d_in[1];
    const float* bk = (const float*)d_in[2];
    const float* Wq = (const float*)d_in[3];
    const float* bq = (const float*)d_in[4];
    const float* Wv = (const float*)d_in[5];
    const float* bv = (const float*)d_in[6];
    const float* Wl = (const float*)d_in[7];
    const float* bl = (const float*)d_in[8];
    float* out = (float*)d_out;

    char* w = (char*)d_ws;
    f16*   xs_h = (f16*)w;   w += (size_t)M_*D_*2;   // 16.8 MB
    f16*   WvlH = (f16*)w;   w += (size_t)D_*D_*2;
    f16*   WlH  = (f16*)w;   w += (size_t)D_*D_*2;
    f16*   WvT  = (f16*)w;   w += (size_t)D_*D_*2;
    f16*   WkT  = (f16*)w;   w += (size_t)D_*D_*2;
    f16*   WqT  = (f16*)w;   w += (size_t)D_*D_*2;
    float* Mm   = (float*)w; w += (size_t)D_*D_*4;   // 1 MB
    float* MT   = (float*)w; w += (size_t)D_*D_*4;   // 1 MB
    // zero region: xsSum | yG | S0G contiguous (one async memset)
    float* xsSum= (float*)w; w += (size_t)B_*D_*4;
    float* yG   = (float*)w; w += (size_t)B_*D_*4;
    float* S0G  = (float*)w; w += 4*4;
    f16*   uH   = (f16*)w;   w += (size_t)B_*D_*2;
    float* hG   = (float*)w; w += (size_t)B_*D_*4;
    float* uG   = (float*)w; w += (size_t)B_*D_*4;
    float* t1   = (float*)w; w += (size_t)D_*4;
    float* t2   = (float*)w; w += (size_t)D_*4;
    float* bvlG = (float*)w; w += (size_t)D_*4;
    float* c1G  = (float*)w; w += 4*4;
    float* c2G  = (float*)w; w += 4*4;
    float* t12  = (float*)w; w += 4;
    if ((size_t)(w - (char*)d_ws) > ws_size) return;  // fail loudly

    hipMemsetAsync(xsSum, 0, (2*B_*D_ + 4)*sizeof(float), stream);

    void* args[] = {
        (void*)&xs, (void*)&Wv, (void*)&Wk, (void*)&Wq, (void*)&Wl,
        (void*)&bv, (void*)&bk, (void*)&bq,
        (void*)&xs_h, (void*)&xsSum,
        (void*)&WvT, (void*)&WkT, (void*)&WqT, (void*)&WlH,
        (void*)&WvlH, (void*)&bvlG, (void*)&Mm, (void*)&MT,
        (void*)&t1, (void*)&t2, (void*)&t12,
        (void*)&hG, (void*)&c1G, (void*)&yG, (void*)&S0G,
        (void*)&uG, (void*)&uH, (void*)&c2G
    };
    hipLaunchCooperativeKernel(front_kernel, dim3(512), dim3(256), args, 0, stream);

    vl_gemm<<<dim3(128,4), 256, 0, stream>>>(xs_h, WvlH, bvlG, bl, uH, c2G, S0G, out);
}

// Round 2
// 251.253 us; speedup vs baseline: 1.6013x; 1.6013x over previous
//
#include <hip/hip_runtime.h>
#include <cstdint>

#define B_ 4
#define S_ 4096
#define D_ 512
#define M_ (B_*S_)   // 16384 rows

typedef _Float16 f16;
typedef _Float16 f16x8 __attribute__((ext_vector_type(8)));
typedef _Float16 f16x2 __attribute__((ext_vector_type(2)));
typedef float    f32x4 __attribute__((ext_vector_type(4)));

typedef __attribute__((address_space(1))) void* as1p;
typedef __attribute__((address_space(3))) void* as3p;

__device__ __forceinline__ void gl2lds16(const void* g, void* l) {
    __builtin_amdgcn_global_load_lds((as1p)g, (as3p)l, 16, 0, 0);
}

union f16pack { f16x8 v8; f16x2 v2[4]; };

__device__ __forceinline__ float agent_load_f(const float* p) {
    return __hip_atomic_load(p, __ATOMIC_RELAXED, __HIP_MEMORY_SCOPE_AGENT);
}
__device__ __forceinline__ int agent_load_i(const int* p) {
    return __hip_atomic_load(p, __ATOMIC_RELAXED, __HIP_MEMORY_SCOPE_AGENT);
}

// ---------------- weight prep: v<64: Wv transpose tile; v in 64..127: Wl f16 cast ----------------
__device__ __forceinline__ void weight_job(int v, int t, char* SMEM,
    const float* __restrict__ Wv, const float* __restrict__ Wl,
    f16* __restrict__ WvT, f16* __restrict__ WlH)
{
    const int z = v >> 6, tile_id = v & 63;
    if (z == 1) {    // Wl cast (row-major f16)
        const size_t base = (size_t)tile_id*4096 + (size_t)t*16;
        const float4* s4 = (const float4*)(Wl + base);
        float4 a0 = s4[0], a1 = s4[1], a2 = s4[2], a3 = s4[3];
        f16x8 o0, o1;
        o0[0]=(f16)a0.x; o0[1]=(f16)a0.y; o0[2]=(f16)a0.z; o0[3]=(f16)a0.w;
        o0[4]=(f16)a1.x; o0[5]=(f16)a1.y; o0[6]=(f16)a1.z; o0[7]=(f16)a1.w;
        o1[0]=(f16)a2.x; o1[1]=(f16)a2.y; o1[2]=(f16)a2.z; o1[3]=(f16)a2.w;
        o1[4]=(f16)a3.x; o1[5]=(f16)a3.y; o1[6]=(f16)a3.z; o1[7]=(f16)a3.w;
        *(f16x8*)(WlH + base)     = o0;
        *(f16x8*)(WlH + base + 8) = o1;
        return;
    }
    // Wv transpose tile -> WvT[j][i] = Wv[i][j]
    float (*tile)[68] = (float(*)[68])SMEM;
    const int bx = tile_id & 7, by = tile_id >> 3;
    const int i0 = bx*64, j0 = by*64;
    const int r = t >> 2, cpart = (t & 3)*16;
    {
        const float4* s4 = (const float4*)(Wv + (size_t)(i0 + r)*512 + j0 + cpart);
        float4 a0 = s4[0], a1 = s4[1], a2 = s4[2], a3 = s4[3];
        *(float4*)&tile[r][cpart]    = a0;
        *(float4*)&tile[r][cpart+4]  = a1;
        *(float4*)&tile[r][cpart+8]  = a2;
        *(float4*)&tile[r][cpart+12] = a3;
    }
    __syncthreads();
    const int c = t >> 2, rpart = (t & 3)*16;
    f16x8 o0, o1;
    #pragma unroll
    for (int q = 0; q < 8; q++) o0[q] = (f16)tile[rpart + q][c];
    #pragma unroll
    for (int q = 0; q < 8; q++) o1[q] = (f16)tile[rpart + 8 + q][c];
    *(f16x8*)(WvT + (size_t)(j0 + c)*512 + i0 + rpart)     = o0;
    *(f16x8*)(WvT + (size_t)(j0 + c)*512 + i0 + rpart + 8) = o1;
}

// ---------------- xs cast + column sums (j = 0..255, 64 rows each) ----------------
__device__ __forceinline__ void xs_job64(int j, int t, char* SMEM,
    const float* __restrict__ xs, f16* __restrict__ xs_h,
    float* __restrict__ xsSum)
{
    float* red = (float*)SMEM;   // [4][512]
    const int w = t >> 6, l = t & 63;
    const int col = l * 8;
    float acc[8] = {0,0,0,0,0,0,0,0};
    for (int c = 0; c < 16; c++) {
        int row = j*64 + c*4 + w;
        const float4* p = (const float4*)(xs + (size_t)row*512 + col);
        float4 a = p[0], b = p[1];
        f16x8 o;
        o[0]=(f16)a.x; o[1]=(f16)a.y; o[2]=(f16)a.z; o[3]=(f16)a.w;
        o[4]=(f16)b.x; o[5]=(f16)b.y; o[6]=(f16)b.z; o[7]=(f16)b.w;
        *(f16x8*)(xs_h + (size_t)row*512 + col) = o;
        acc[0]+=a.x; acc[1]+=a.y; acc[2]+=a.z; acc[3]+=a.w;
        acc[4]+=b.x; acc[5]+=b.y; acc[6]+=b.z; acc[7]+=b.w;
    }
    #pragma unroll
    for (int q = 0; q < 8; q++) red[w*512 + col + q] = acc[q];
    __syncthreads();
    const int b = j >> 6;
    #pragma unroll
    for (int k = 0; k < 2; k++) {
        int c = t + k*256;
        atomicAdd(&xsSum[b*512 + c], red[c] + red[512+c] + red[1024+c] + red[1536+c]);
    }
}

// ---------------- chained matvec partial (helper rank q handles d in [q*128, q*128+128)):
//   g[d] = rowW[d,:].v + sbias*rbias[d];  outc += sum_d g[d]*cdot[d];
//   outv[j] += sum_d colW[d][j]*g[d]   (atomicAdd partials) ----------------
__device__ __forceinline__ void chain_partial(int q, int t, char* SMEM,
    const float* __restrict__ rowW, const float* __restrict__ colW,
    const float* __restrict__ rbias, const float* __restrict__ cdot,
    float sbias, const float* __restrict__ vsrc,
    float* __restrict__ outv, float* __restrict__ outc)
{
    float* vv = (float*)SMEM;        // 512
    float* gg = vv + 512;            // 128
    for (int i = t; i < 512; i += 256)
        vv[i] = agent_load_f(vsrc + i);
    __syncthreads();
    const int w = t >> 6, l = t & 63, p = l & 15, g4 = l >> 4;
    float vs[32];
    #pragma unroll
    for (int c = 0; c < 32; c++) vs[c] = vv[p*32 + c];
    const int d0 = q*128;
    float cacc = 0.f;
    for (int it = 0; it < 8; it++) {
        const int r = d0 + w*32 + it*4 + g4;
        const float4* wr = (const float4*)(rowW + (size_t)r*512 + p*32);
        float acc = 0.f;
        #pragma unroll
        for (int u4 = 0; u4 < 8; u4++) {
            float4 a = wr[u4];
            acc += a.x*vs[u4*4] + a.y*vs[u4*4+1] + a.z*vs[u4*4+2] + a.w*vs[u4*4+3];
        }
        acc += __shfl_xor(acc, 1);
        acc += __shfl_xor(acc, 2);
        acc += __shfl_xor(acc, 4);
        acc += __shfl_xor(acc, 8);
        if (p == 0) {
            float gv = acc + sbias * rbias[r];
            gg[r - d0] = gv;
            cacc += gv * cdot[r];
        }
    }
    if (p == 0) atomicAdd(outc, cacc);
    __syncthreads();
    float a0 = 0.f, a1 = 0.f;
    const int c0 = 2*t;
    for (int d = 0; d < 128; d++) {
        const float gd = gg[d];
        const float2 wv2 = *(const float2*)(colW + (size_t)(d0 + d)*512 + c0);
        a0 += gd * wv2.x;
        a1 += gd * wv2.y;
    }
    atomicAdd(&outv[c0], a0);
    atomicAdd(&outv[c0 + 1], a1);
}

// ---------------- k1: weight prep (0..127) || xs cast+sum (128..383) + h-chain tail ----------------
__global__ __launch_bounds__(256, 2) void k1_kernel(
    const float* __restrict__ xs,
    const float* __restrict__ Wv, const float* __restrict__ Wl,
    const float* __restrict__ Wk, const float* __restrict__ Wq,
    const float* __restrict__ bk, const float* __restrict__ bq,
    f16* __restrict__ xs_h, float* __restrict__ xsSum,
    f16* __restrict__ WvT, f16* __restrict__ WlH,
    float* __restrict__ hG, float* __restrict__ c1G, int* __restrict__ tickA)
{
    __shared__ __attribute__((aligned(16))) char SMEM[17408];
    __shared__ int oldv;
    const int blk = blockIdx.x, t = threadIdx.x;
    if (blk < 128) { weight_job(blk, t, SMEM, Wv, Wl, WvT, WlH); return; }
    const int j = blk - 128, b = j >> 6;
    xs_job64(j, t, SMEM, xs, xs_h, xsSum);
    __threadfence();
    __syncthreads();
    if (t == 0) oldv = atomicAdd(&tickA[b], 1);
    __syncthreads();
    const int old = oldv;
    if (old < 60) return;
    if (t == 0) {
        while (agent_load_i(&tickA[b]) < 64) __builtin_amdgcn_s_sleep(8);
    }
    __syncthreads();
    __threadfence();
    // g1 = Wk@xsSum_b + 4096*bk ; hG[b] += Wq^T g1 (partial) ; c1[b] += bq.g1 (partial)
    chain_partial(old - 60, t, SMEM, Wk, Wq, bk, bq, 4096.0f,
                  xsSum + b*512, hG + (size_t)b*512, c1G + b);
}

// ---------------- Wvl GEMM job (v = 0..63): WvlH = WlH @ WvT^T, + bvl ----------------
__device__ __forceinline__ void wvl_job(int v, int t, char* SMEM,
    const f16* __restrict__ WlH, const f16* __restrict__ WvT,
    const float* __restrict__ Wl, const float* __restrict__ bv,
    f16* __restrict__ WvlH, float* __restrict__ bvlG)
{
    f16* lA = (f16*)SMEM;          // 4KB
    f16* lB = lA + 64*32;          // 4KB
    const int bx = v & 7, by = v >> 3;
    const int i0 = bx*64, j0 = by*64;
    const int lane = t & 63, wid = t >> 6;
    const int wm = (wid & 1)*32, wn = (wid >> 1)*32;
    const int srow = t >> 2, skb = (t & 3) << 4;
    const long aoff = (long)(i0 + srow)*1024 + skb;
    const long boff = (long)(j0 + srow)*1024 + skb;
    const unsigned wbase = (unsigned)wid << 10;
    f32x4 acc[2][2] = {};
    const int ael = (wm + (lane & 15))*32 + ((lane >> 4) << 3);
    const int bel = (wn + (lane & 15))*32 + ((lane >> 4) << 3);
    for (int k0 = 0; k0 < 512; k0 += 32) {
        __syncthreads();
        gl2lds16((const char*)WlH + aoff + k0*2, (char*)lA + wbase);
        gl2lds16((const char*)WvT + boff + k0*2, (char*)lB + wbase);
        __syncthreads();
        f16x8 af[2], bf[2];
        af[0] = *(const f16x8*)(lA + ael);
        af[1] = *(const f16x8*)(lA + ael + 512);
        bf[0] = *(const f16x8*)(lB + bel);
        bf[1] = *(const f16x8*)(lB + bel + 512);
        #pragma unroll
        for (int i = 0; i < 2; i++)
            #pragma unroll
            for (int j = 0; j < 2; j++)
                acc[i][j] = __builtin_amdgcn_mfma_f32_16x16x32_f16(af[i], bf[j], acc[i][j], 0, 0, 0);
    }
    const int rb = wm + ((lane >> 4) << 2);
    const int cb = wn + (lane & 15);
    #pragma unroll
    for (int i = 0; i < 2; i++)
        #pragma unroll
        for (int j = 0; j < 2; j++)
            #pragma unroll
            for (int r = 0; r < 4; r++)
                WvlH[(size_t)(i0 + rb + i*16 + r)*512 + j0 + cb + j*16] = (f16)acc[i][j][r];
    if (by == 0) {
        int r = t >> 2, part = t & 3;
        const float4* wr = (const float4*)(Wl + (size_t)(i0+r)*512 + part*128);
        const float4* bp = (const float4*)(bv + part*128);
        float s = 0.f;
        #pragma unroll 8
        for (int q = 0; q < 32; q++) {
            float4 wv4 = wr[q], b4 = bp[q];
            s += wv4.x*b4.x + wv4.y*b4.y + wv4.z*b4.z + wv4.w*b4.w;
        }
        s += __shfl_xor(s, 1);
        s += __shfl_xor(s, 2);
        if (part == 0) bvlG[i0 + r] = s;
    }
}

// ---------------- z pass (z = 0..511, 32 rows): iv = 1/(4096+(xs.h+c1)/512); y += iv*xs, S0 += iv ----------------
__device__ __forceinline__ void z_job(int z, int t, char* SMEM,
    const f16* __restrict__ xs_h, const float* __restrict__ hG,
    const float* __restrict__ c1G, float* __restrict__ yG, float* __restrict__ S0G)
{
    float* hs    = (float*)SMEM;      // 512
    float* yred  = hs + 512;          // [4][512]
    float* s0red = yred + 2048;       // [4]
    const int b = z >> 7, w = t >> 6, l = t & 63;
    hs[t] = hG[(size_t)b*512 + t]; hs[t+256] = hG[(size_t)b*512 + t + 256];
    __syncthreads();
    const float c1 = c1G[b];
    float hx[8];
    #pragma unroll
    for (int q = 0; q < 8; q++) hx[q] = hs[l*8+q];
    float yacc[8] = {0,0,0,0,0,0,0,0};
    float s0acc = 0.f;
    for (int it = 0; it < 8; it++) {
        int row = z*32 + w*8 + it;
        f16x8 v = *(const f16x8*)(xs_h + (size_t)row*512 + l*8);
        float xf[8];
        #pragma unroll
        for (int q = 0; q < 8; q++) xf[q] = (float)v[q];
        float d = 0.f;
        #pragma unroll
        for (int q = 0; q < 8; q++) d += xf[q]*hx[q];
        #pragma unroll
        for (int m = 1; m < 64; m <<= 1) d += __shfl_xor(d, m);
        float zz = 4096.0f + (d + c1)*(1.0f/512.0f);
        float iv = 1.0f/zz;
        s0acc += iv;
        #pragma unroll
        for (int q = 0; q < 8; q++) yacc[q] += iv*xf[q];
    }
    #pragma unroll
    for (int q = 0; q < 8; q++) yred[w*512 + l*8+q] = yacc[q];
    if (l == 0) s0red[w] = s0acc;
    __syncthreads();
    #pragma unroll
    for (int k = 0; k < 2; k++) {
        int c = t + k*256;
        atomicAdd(&yG[b*512 + c], yred[c]+yred[512+c]+yred[1024+c]+yred[1536+c]);
    }
    if (t == 0) atomicAdd(&S0G[b], s0red[0]+s0red[1]+s0red[2]+s0red[3]);
}

// ---------------- k3: Wvl GEMM (0..63) || z pass (64..575) + u-chain tail ----------------
__global__ __launch_bounds__(256, 2) void k3_kernel(
    const f16* __restrict__ xs_h,
    const float* __restrict__ hG, const float* __restrict__ c1G,
    float* __restrict__ yG, float* __restrict__ S0G,
    const f16* __restrict__ WlH, const f16* __restrict__ WvT,
    const float* __restrict__ Wl, const float* __restrict__ bv,
    f16* __restrict__ WvlH, float* __restrict__ bvlG,
    const float* __restrict__ Wk, const float* __restrict__ Wq,
    const float* __restrict__ bk, const float* __restrict__ bq,
    float* __restrict__ uG, f16* __restrict__ uH, float* __restrict__ c2G,
    int* __restrict__ tickZ, int* __restrict__ tickU)
{
    __shared__ __attribute__((aligned(16))) char SMEM[10304];
    __shared__ int oldv, oldv2;
    const int blk = blockIdx.x, t = threadIdx.x;
    if (blk < 64) { wvl_job(blk, t, SMEM, WlH, WvT, Wl, bv, WvlH, bvlG); return; }
    const int z = blk - 64, b = z >> 7;
    z_job(z, t, SMEM, xs_h, hG, c1G, yG, S0G);
    __threadfence();
    __syncthreads();
    if (t == 0) oldv = atomicAdd(&tickZ[b], 1);
    __syncthreads();
    const int old = oldv;
    if (old < 124) return;
    if (t == 0) {
        while (agent_load_i(&tickZ[b]) < 128) __builtin_amdgcn_s_sleep(8);
    }
    __syncthreads();
    __threadfence();
    const float S0b = agent_load_f(&S0G[b]);
    // g2 = Wq@y_b + S0*bq ; uG[b] += Wk^T g2 (partial) ; c2[b] += bk.g2 (partial)
    chain_partial(old - 124, t, SMEM, Wq, Wk, bq, bk, S0b,
                  yG + b*512, uG + (size_t)b*512, c2G + b);
    __threadfence();
    __syncthreads();
    if (t == 0) oldv2 = atomicAdd(&tickU[b], 1);
    __syncthreads();
    if (oldv2 == 3) {   // last helper finalizes f16 cast of u
        __threadfence();
        for (int i = t; i < 512; i += 256)
            uH[(size_t)b*512 + i] = (f16)agent_load_f(uG + (size_t)b*512 + i);
    }
}

// ---------------- vl_gemm: out = tanh(rs*(xs@Wvl^T + bvl) + bl), rs fused via v_dot2 ----------------
__global__ __launch_bounds__(256, 2) void vl_gemm(const f16* __restrict__ A,
    const f16* __restrict__ Bt, const float* __restrict__ bvlG,
    const float* __restrict__ blG, const f16* __restrict__ uH,
    const float* __restrict__ c2G, const float* __restrict__ S0G,
    float* __restrict__ out)
{
    constexpr int K = 512;
    __shared__ f16 lA[128*32];
    __shared__ f16 lB[128*32];
    __shared__ float rsbuf[128];
    const int t = threadIdx.x;
    const int m0 = blockIdx.x*128, n0 = blockIdx.y*128;
    const int lane = t & 63, wid = t >> 6;
    const int wm = (wid & 1) << 6, wn = (wid >> 1) << 6;
    const int srow = t >> 2, skb = (t & 3) << 4;
    const long aoff0 = (long)(m0 + srow)*(K*2) + skb;
    const long aoff1 = aoff0 + 64L*(K*2);
    const long boff0 = (long)(n0 + srow)*(K*2) + skb;
    const long boff1 = boff0 + 64L*(K*2);
    char* ldsA = (char*)lA;
    char* ldsB = (char*)lB;
    const unsigned wbase = (unsigned)wid << 10;
    const char* Ab = (const char*)A;
    const char* Bb = (const char*)Bt;

    const int bat = blockIdx.x >> 5;          // 32 m-tiles per batch
    const f16* u = uH + bat*512;
    const int ku = (lane >> 4) << 3;

    f32x4 acc[4][4] = {};
    float racc[4] = {0.f,0.f,0.f,0.f};
    const int ael = (wm + (lane & 15))*32 + ku;
    const int bel = (wn + (lane & 15))*32 + ku;

    for (int k0 = 0; k0 < K; k0 += 32) {
        __syncthreads();
        const long kb = (long)k0*2;
        gl2lds16(Ab + aoff0 + kb, ldsA + wbase);
        gl2lds16(Ab + aoff1 + kb, ldsA + 4096 + wbase);
        gl2lds16(Bb + boff0 + kb, ldsB + wbase);
        gl2lds16(Bb + boff1 + kb, ldsB + 4096 + wbase);
        __syncthreads();
        f16x8 af[4], bf[4];
        #pragma unroll
        for (int i = 0; i < 4; i++) af[i] = *(const f16x8*)(lA + ael + i*512);
        #pragma unroll
        for (int j = 0; j < 4; j++) bf[j] = *(const f16x8*)(lB + bel + j*512);
        f16pack up; up.v8 = *(const f16x8*)(u + k0 + ku);
        #pragma unroll
        for (int i = 0; i < 4; i++) {
            f16pack ap; ap.v8 = af[i];
            #pragma unroll
            for (int q = 0; q < 4; q++)
                racc[i] = __builtin_amdgcn_fdot2(ap.v2[q], up.v2[q], racc[i], false);
        }
        #pragma unroll
        for (int i = 0; i < 4; i++)
            #pragma unroll
            for (int j = 0; j < 4; j++)
                acc[i][j] = __builtin_amdgcn_mfma_f32_16x16x32_f16(af[i], bf[j], acc[i][j], 0, 0, 0);
    }

    #pragma unroll
    for (int i = 0; i < 4; i++) {
        racc[i] += __shfl_xor(racc[i], 16);
        racc[i] += __shfl_xor(racc[i], 32);
    }
    const float S0 = S0G[bat], c2 = c2G[bat];
    if (wid < 2 && lane < 16) {
        #pragma unroll
        for (int i = 0; i < 4; i++)
            rsbuf[wm + i*16 + lane] = S0 + (racc[i] + c2)*(1.0f/512.0f);
    }
    __syncthreads();

    const int crb = m0 + wm + ((lane >> 4) << 2);
    const int ccb = n0 + wn + (lane & 15);
    const int lrb = wm + ((lane >> 4) << 2);
    #pragma unroll
    for (int i = 0; i < 4; i++) {
        float rsv[4];
        #pragma unroll
        for (int r = 0; r < 4; r++) rsv[r] = rsbuf[lrb + i*16 + r];
        #pragma unroll
        for (int j = 0; j < 4; j++) {
            int c = ccb + j*16;
            float bb = bvlG[c], bo = blG[c];
            #pragma unroll
            for (int r = 0; r < 4; r++) {
                float yv = rsv[r]*(acc[i][j][r] + bb) + bo;
                float e2 = __expf(2.0f*yv);
                out[(size_t)(crb + i*16 + r)*512 + c] = 1.0f - 2.0f/(e2 + 1.0f);
            }
        }
    }
}

extern "C" void kernel_launch(void* const* d_in, const int* in_sizes, int n_in,
                              void* d_out, int out_size, void* d_ws, size_t ws_size,
                              hipStream_t stream)
{
    const float* xs = (const float*)d_in[0];
    const float* Wk = (const float*)d_in[1];
    const float* bk = (const float*)d_in[2];
    const float* Wq = (const float*)d_in[3];
    const float* bq = (const float*)d_in[4];
    const float* Wv = (const float*)d_in[5];
    const float* bv = (const float*)d_in[6];
    const float* Wl = (const float*)d_in[7];
    const float* bl = (const float*)d_in[8];
    float* out = (float*)d_out;

    char* w = (char*)d_ws;
    f16*   xs_h = (f16*)w;   w += (size_t)M_*D_*2;   // 16.8 MB
    f16*   WvlH = (f16*)w;   w += (size_t)D_*D_*2;
    f16*   WlH  = (f16*)w;   w += (size_t)D_*D_*2;
    f16*   WvT  = (f16*)w;   w += (size_t)D_*D_*2;
    f16*   uH   = (f16*)w;   w += (size_t)B_*D_*2;
    float* bvlG = (float*)w; w += (size_t)D_*4;
    // ---- zero region (one async memset, also resets tickets each graph replay) ----
    char* z0 = w;
    float* xsSum= (float*)w; w += (size_t)B_*D_*4;
    float* yG   = (float*)w; w += (size_t)B_*D_*4;
    float* hG   = (float*)w; w += (size_t)B_*D_*4;
    float* uG   = (float*)w; w += (size_t)B_*D_*4;
    float* S0G  = (float*)w; w += B_*4;
    float* c1G  = (float*)w; w += B_*4;
    float* c2G  = (float*)w; w += B_*4;
    int*   tickA= (int*)w;   w += B_*4;
    int*   tickZ= (int*)w;   w += B_*4;
    int*   tickU= (int*)w;   w += B_*4;
    const size_t zbytes = (size_t)(w - z0);
    if ((size_t)(w - (char*)d_ws) > ws_size) return;  // fail loudly

    hipMemsetAsync(z0, 0, zbytes, stream);

    k1_kernel<<<384, 256, 0, stream>>>(xs, Wv, Wl, Wk, Wq, bk, bq,
        xs_h, xsSum, WvT, WlH, hG, c1G, tickA);

    k3_kernel<<<576, 256, 0, stream>>>(xs_h, hG, c1G, yG, S0G,
        WlH, WvT, Wl, bv, WvlH, bvlG, Wk, Wq, bk, bq,
        uG, uH, c2G, tickZ, tickU);

    vl_gemm<<<dim3(128,4), 256, 0, stream>>>(xs_h, WvlH, bvlG, bl, uH, c2G, S0G, out);
}